// Round 4
// baseline (1046.711 us; speedup 1.0000x reference)
//
#include <hip/hip_runtime.h>
#include <math.h>

#define DIM 10
#define NTILE 256

// ---------------------------------------------------------------------------
// K0 fused init:
//   hbuf[node] = (depth<=2) ? h_in[node] : 0   (stride HS, pads = 0)
//   x[node]    = 0                             (stride XS, incl. pads)
// ---------------------------------------------------------------------------
template<int XS, int HS>
__global__ void init_kernel(const float* __restrict__ hsrc,   // stride DIM
                            float* __restrict__ hdst,         // stride HS
                            float* __restrict__ x,            // stride XS
                            const int* __restrict__ depth,
                            int n)
{
    __shared__ float sh[NTILE * 11];
    const int t = threadIdx.x;
    const int base = blockIdx.x * NTILE;

    const long gbase = (long)base * DIM;
    const long glim  = (long)n * DIM;
    for (int idx = t; idx < NTILE * DIM; idx += NTILE) {
        long g = gbase + idx;
        float v = (g < glim) ? hsrc[g] : 0.0f;
        sh[(idx / DIM) * 11 + (idx % DIM)] = v;
    }
    __syncthreads();

    const int node = base + t;
    if (node < n && depth[node] > 2) {          // inactive at iter 0
        #pragma unroll
        for (int c = 0; c < DIM; ++c) sh[t * 11 + c] = 0.0f;
    }
    __syncthreads();

    const long obase = (long)base * HS;
    const long olim  = (long)n * HS;
    for (int idx = t; idx < NTILE * HS; idx += NTILE) {
        long g = obase + idx;
        if (g < olim) {
            int nl = idx / HS, c = idx % HS;
            hdst[g] = (c < DIM) ? sh[nl * 11 + c] : 0.0f;
        }
    }

    // zero this tile's x range (coalesced float4)
    float4* x4 = reinterpret_cast<float4*>(x);
    const long zb = (long)base * XS / 4;
    const long zl = (long)n * XS / 4;
    for (int i4 = t; i4 < NTILE * XS / 4; i4 += NTILE) {
        long g = zb + i4;
        if (g < zl) x4[g] = make_float4(0.0f, 0.0f, 0.0f, 0.0f);
    }
}

// ---------------------------------------------------------------------------
// edge scatter: thread per (edge, component); HW non-returning atomics.
// depth pre-filter: depth[] is 2 MB -> L2-resident; skipping inactive senders
// avoids fetching their 64B h-line entirely (h==0 there, add is a no-op).
// ---------------------------------------------------------------------------
template<int XS, int HS>
__global__ void scatter_add_kernel(const int* __restrict__ recv,
                                   const int* __restrict__ send,
                                   const int* __restrict__ depth,
                                   const float* __restrict__ hm,  // stride HS
                                   float* __restrict__ x,         // stride XS
                                   int ne, int iter)
{
    const int tid = blockIdx.x * blockDim.x + threadIdx.x;
    const int e = tid / DIM;
    if (e >= ne) return;
    const int c = tid - e * DIM;
    const int s = send[e];
    if (depth[s] + iter > 2) return;            // inactive sender: h row == 0
    const float v = hm[(long)s * HS + c];
    if (v != 0.0f) {
        const int r = recv[e];
        unsafeAtomicAdd(x + (long)r * XS + c, v);
    }
}

// ---------------------------------------------------------------------------
// GRU update, LDS tile-staged.
//   h_new = gru(x, h) for active nodes (depth+iter<=2), else h (==0)
//   if NEXTMASK: additionally zero nodes inactive at iter+1 (fuses next mask)
//   if ZEROX:    rewrite this tile's x range to 0 (fuses next zero_x)
// Writes `out` with runtime stride OS.
// ---------------------------------------------------------------------------
template<int XS, int HS, int NEXTMASK, int ZEROX>
__global__ void gru_kernel(const float* __restrict__ x,
                           float* __restrict__ xw,              // same as x, for ZEROX
                           const float* __restrict__ h,
                           float* __restrict__ out, int OS,
                           const int* __restrict__ depth, int iter, int n,
                           const float* __restrict__ Wz, const float* __restrict__ bz,
                           const float* __restrict__ Uz, const float* __restrict__ buz,
                           const float* __restrict__ Wr, const float* __restrict__ br,
                           const float* __restrict__ Ur, const float* __restrict__ bur,
                           const float* __restrict__ Wh, const float* __restrict__ bh,
                           const float* __restrict__ Uh, const float* __restrict__ buh)
{
    __shared__ float sx[NTILE * 17];
    __shared__ float shh[NTILE * 17];
    __shared__ float sW[6][100];
    __shared__ float sb[3][10];

    const int t = threadIdx.x;
    if (t < 100) {
        sW[0][t] = Wz[t]; sW[1][t] = Uz[t];
        sW[2][t] = Wr[t]; sW[3][t] = Ur[t];
        sW[4][t] = Wh[t]; sW[5][t] = Uh[t];
    }
    if (t < 10) {
        sb[0][t] = bz[t] + buz[t];
        sb[1][t] = br[t] + bur[t];
        sb[2][t] = bh[t] + buh[t];
    }

    const int base = blockIdx.x * NTILE;

    // ---- stage x tile (float4, coalesced) ----
    {
        const int tile4 = NTILE * XS / 4;
        const long g4base = (long)base * XS / 4;
        const long g4lim  = (long)n * XS / 4;
        const float4* xg = reinterpret_cast<const float4*>(x);
        for (int i4 = t; i4 < tile4; i4 += NTILE) {
            long g = g4base + i4;
            if (g < g4lim) {
                float4 v = xg[g];
                float vv[4] = {v.x, v.y, v.z, v.w};
                int f = i4 * 4;
                int nl = f / XS, c = f % XS;
                #pragma unroll
                for (int k = 0; k < 4; ++k) {
                    sx[nl * 17 + c] = vv[k];
                    if (++c == XS) { c = 0; ++nl; }
                }
            }
        }
    }
    // ---- stage h tile (float4, coalesced) ----
    {
        const int tile4 = NTILE * HS / 4;
        const long g4base = (long)base * HS / 4;
        const long g4lim  = (long)n * HS / 4;
        const float4* hg = reinterpret_cast<const float4*>(h);
        for (int i4 = t; i4 < tile4; i4 += NTILE) {
            long g = g4base + i4;
            if (g < g4lim) {
                float4 v = hg[g];
                float vv[4] = {v.x, v.y, v.z, v.w};
                int f = i4 * 4;
                int nl = f / HS, c = f % HS;
                #pragma unroll
                for (int k = 0; k < 4; ++k) {
                    shh[nl * 17 + c] = vv[k];
                    if (++c == HS) { c = 0; ++nl; }
                }
            }
        }
    }
    __syncthreads();

    // fused re-zero of x for the next iteration (tile data now lives in LDS)
    if (ZEROX) {
        float4* x4 = reinterpret_cast<float4*>(xw);
        const long zb = (long)base * XS / 4;
        const long zl = (long)n * XS / 4;
        for (int i4 = t; i4 < NTILE * XS / 4; i4 += NTILE) {
            long g = zb + i4;
            if (g < zl) x4[g] = make_float4(0.0f, 0.0f, 0.0f, 0.0f);
        }
    }

    const int node = base + t;
    const bool valid = node < n;
    const int dep = valid ? depth[node] : 99;
    const bool active = valid && (dep + iter <= 2);

    float xv[DIM], hv[DIM], outv[DIM];
    #pragma unroll
    for (int j = 0; j < DIM; ++j) {
        xv[j] = sx[t * 17 + j];
        hv[j] = shh[t * 17 + j];
    }

    if (active) {
        float zz[DIM], rr[DIM];
        #pragma unroll
        for (int i = 0; i < DIM; ++i) {
            float az = sb[0][i];
            float ar = sb[1][i];
            #pragma unroll
            for (int j = 0; j < DIM; ++j) {
                az = fmaf(xv[j], sW[0][i * DIM + j], az);
                az = fmaf(hv[j], sW[1][i * DIM + j], az);
                ar = fmaf(xv[j], sW[2][i * DIM + j], ar);
                ar = fmaf(hv[j], sW[3][i * DIM + j], ar);
            }
            zz[i] = 1.0f / (1.0f + __expf(-az));
            rr[i] = 1.0f / (1.0f + __expf(-ar));
        }
        float rh[DIM];
        #pragma unroll
        for (int j = 0; j < DIM; ++j) rh[j] = rr[j] * hv[j];
        #pragma unroll
        for (int i = 0; i < DIM; ++i) {
            float ah = sb[2][i];
            #pragma unroll
            for (int j = 0; j < DIM; ++j) {
                ah = fmaf(xv[j], sW[4][i * DIM + j], ah);
                ah = fmaf(rh[j], sW[5][i * DIM + j], ah);
            }
            float th = tanhf(ah);
            outv[i] = zz[i] * hv[i] + (1.0f - zz[i]) * th;
        }
    } else {
        #pragma unroll
        for (int i = 0; i < DIM; ++i) outv[i] = hv[i];   // inactive: h already 0
    }

    if (NEXTMASK) {                 // fold next iteration's where(active,...,0)
        const bool keep = valid && (dep + iter + 1 <= 2);
        if (!keep) {
            #pragma unroll
            for (int i = 0; i < DIM; ++i) outv[i] = 0.0f;
        }
    }

    __syncthreads();   // everyone done reading sx before we overwrite it
    #pragma unroll
    for (int i = 0; i < DIM; ++i) sx[t * 17 + i] = outv[i];
    __syncthreads();

    // ---- flush NTILE*OS floats coalesced (pad components -> 0) ----
    const long obase = (long)base * OS;
    const long olim  = (long)n * OS;
    for (int idx = t; idx < NTILE * OS; idx += NTILE) {
        long g = obase + idx;
        if (g < olim) {
            int nl = idx / OS, c = idx % OS;
            out[g] = (c < DIM) ? sx[nl * 17 + c] : 0.0f;
        }
    }
}

// ---------------------------------------------------------------------------
template<int XS, int HS>
static void run_pipeline(const float* h_in, const int* recv, const int* send,
                         const int* depth, float* x, float* hbuf, float* d_out,
                         int n, int ne, hipStream_t stream,
                         const float* Wz, const float* bz, const float* Uz, const float* buz,
                         const float* Wr, const float* br, const float* Ur, const float* bur,
                         const float* Wh, const float* bh, const float* Uh, const float* buh)
{
    const int BLK = 256;
    const int node_blocks = (n + NTILE - 1) / NTILE;
    const int edge_work = ne * DIM;
    const int edge_blocks = (edge_work + BLK - 1) / BLK;

    // -------- iteration 0 (active: depth <= 2) --------
    init_kernel<XS, HS><<<node_blocks, NTILE, 0, stream>>>(h_in, hbuf, x, depth, n);
    scatter_add_kernel<XS, HS><<<edge_blocks, BLK, 0, stream>>>(recv, send, depth, hbuf, x, ne, 0);
    // writes hbuf already masked for iter 1 (depth<=1), and re-zeroes x
    gru_kernel<XS, HS, 1, 1><<<node_blocks, NTILE, 0, stream>>>(x, x, hbuf, hbuf, HS, depth, 0, n,
        Wz, bz, Uz, buz, Wr, br, Ur, bur, Wh, bh, Uh, buh);

    // -------- iteration 1 (active: depth <= 1) --------
    scatter_add_kernel<XS, HS><<<edge_blocks, BLK, 0, stream>>>(recv, send, depth, hbuf, x, ne, 1);
    gru_kernel<XS, HS, 0, 0><<<node_blocks, NTILE, 0, stream>>>(x, x, hbuf, d_out, DIM, depth, 1, n,
        Wz, bz, Uz, buz, Wr, br, Ur, bur, Wh, bh, Uh, buh);
}

extern "C" void kernel_launch(void* const* d_in, const int* in_sizes, int n_in,
                              void* d_out, int out_size, void* d_ws, size_t ws_size,
                              hipStream_t stream) {
    const float* h_in  = (const float*)d_in[0];
    const int*   edges = (const int*)d_in[1];
    const int*   depth = (const int*)d_in[2];
    const float* Wz  = (const float*)d_in[3];
    const float* bz  = (const float*)d_in[4];
    const float* Uz  = (const float*)d_in[5];
    const float* buz = (const float*)d_in[6];
    const float* Wr  = (const float*)d_in[7];
    const float* br  = (const float*)d_in[8];
    const float* Ur  = (const float*)d_in[9];
    const float* bur = (const float*)d_in[10];
    const float* Wh  = (const float*)d_in[11];
    const float* bh  = (const float*)d_in[12];
    const float* Uh  = (const float*)d_in[13];
    const float* buh = (const float*)d_in[14];

    const int n  = in_sizes[0] / DIM;       // 500,000
    const int ne = in_sizes[1] / 2;         // 8,000,000
    const int* recv = edges;
    const int* send = edges + ne;

    const size_t padded_need = (size_t)n * 16 * sizeof(float) * 2;   // x + h, 64 MB

    if (ws_size >= padded_need) {
        float* x    = (float*)d_ws;                 // [n*16]
        float* hbuf = (float*)d_ws + (size_t)n * 16;
        run_pipeline<16, 16>(h_in, recv, send, depth, x, hbuf, (float*)d_out,
                             n, ne, stream,
                             Wz, bz, Uz, buz, Wr, br, Ur, bur, Wh, bh, Uh, buh);
    } else {
        // fallback: unpadded, h lives in d_out
        float* x    = (float*)d_ws;                 // [n*10]
        float* hbuf = (float*)d_out;
        run_pipeline<10, 10>(h_in, recv, send, depth, x, hbuf, (float*)d_out,
                             n, ne, stream,
                             Wz, bz, Uz, buz, Wr, br, Ur, bur, Wh, bh, Uh, buh);
    }
}

// Round 5
// 922.996 us; speedup vs baseline: 1.1340x; 1.1340x over previous
//
#include <hip/hip_runtime.h>
#include <math.h>
#include <stdint.h>

#define DIM 10
#define NTILE 256
#define BKT_LOG 10
#define BKT (1 << BKT_LOG)        // 1024 nodes per bucket
#define MAXNB 512
#define EPW 4096                  // edges per workgroup in binning passes

// ---------------------------------------------------------------------------
// meta layout (u32), placed in ws after x and hbuf:
//   hist[512] | bases[640] | cursor[512]
// ---------------------------------------------------------------------------

__global__ void zero_hist_kernel(uint32_t* __restrict__ hist) {
    hist[threadIdx.x] = 0;        // <<<1,512>>>
}

// pass A: global histogram of kept edges (both endpoints active at iter 0)
__global__ void bin_count_kernel(const int* __restrict__ recv,
                                 const int* __restrict__ send,
                                 const int* __restrict__ depth,
                                 uint32_t* __restrict__ hist,
                                 int ne)
{
    __shared__ uint32_t lh[MAXNB];
    const int t = threadIdx.x;
    for (int i = t; i < MAXNB; i += 256) lh[i] = 0;
    __syncthreads();
    const int base = blockIdx.x * EPW;
    #pragma unroll
    for (int k = 0; k < EPW / 256; ++k) {
        int e = base + k * 256 + t;
        if (e < ne) {
            int r = recv[e], s = send[e];
            if (depth[r] <= 2 && depth[s] <= 2)
                atomicAdd(&lh[r >> BKT_LOG], 1u);
        }
    }
    __syncthreads();
    for (int i = t; i < MAXNB; i += 256)
        if (lh[i]) atomicAdd(&hist[i], lh[i]);
}

// pass B: exclusive scan -> bases[0..NB], cursor[b] = bases[b]   <<<1,512>>>
__global__ void bin_scan_kernel(const uint32_t* __restrict__ hist,
                                uint32_t* __restrict__ bases,
                                uint32_t* __restrict__ cursor,
                                int NB)
{
    __shared__ uint32_t sc[MAXNB];
    const int t = threadIdx.x;
    sc[t] = (t < NB) ? hist[t] : 0;
    __syncthreads();
    for (int off = 1; off < MAXNB; off <<= 1) {
        uint32_t v = sc[t];
        if (t >= off) v += sc[t - off];
        __syncthreads();
        sc[t] = v;
        __syncthreads();
    }
    if (t == 0) bases[0] = 0;
    if (t < NB) {
        bases[t + 1] = sc[t];
        cursor[t] = (t == 0) ? 0u : sc[t - 1];
    }
}

// pass C: emit packed edges into bucket-contiguous bins (in d_out)
//   word = send(19b) | recv_local(10b)<<19 | useful_at_iter1(1b)<<29
__global__ void bin_emit_kernel(const int* __restrict__ recv,
                                const int* __restrict__ send,
                                const int* __restrict__ depth,
                                uint32_t* __restrict__ cursor,
                                uint32_t* __restrict__ bins,
                                int ne, uint32_t cap)
{
    __shared__ uint32_t lh[MAXNB];
    __shared__ uint32_t wgbase[MAXNB];
    __shared__ uint32_t lcur[MAXNB];
    const int t = threadIdx.x;
    for (int i = t; i < MAXNB; i += 256) { lh[i] = 0; lcur[i] = 0; }
    __syncthreads();
    const int base = blockIdx.x * EPW;
    #pragma unroll
    for (int k = 0; k < EPW / 256; ++k) {
        int e = base + k * 256 + t;
        if (e < ne) {
            int r = recv[e], s = send[e];
            if (depth[r] <= 2 && depth[s] <= 2)
                atomicAdd(&lh[r >> BKT_LOG], 1u);
        }
    }
    __syncthreads();
    for (int i = t; i < MAXNB; i += 256)
        if (lh[i]) wgbase[i] = atomicAdd(&cursor[i], lh[i]);
    __syncthreads();
    #pragma unroll
    for (int k = 0; k < EPW / 256; ++k) {
        int e = base + k * 256 + t;
        if (e < ne) {
            int r = recv[e], s = send[e];
            int dr = depth[r], ds = depth[s];
            if (dr <= 2 && ds <= 2) {
                int b = r >> BKT_LOG;
                uint32_t off = atomicAdd(&lcur[b], 1u);
                uint32_t w = (uint32_t)s
                           | ((uint32_t)(r & (BKT - 1)) << 19)
                           | ((dr <= 1 && ds <= 1) ? (1u << 29) : 0u);
                uint32_t idx = wgbase[b] + off;
                if (idx < cap) bins[idx] = w;
            }
        }
    }
}

// ---------------------------------------------------------------------------
// scatter: one WG per bucket; LDS accumulation; sequential x flush (stride 10)
// ---------------------------------------------------------------------------
template<int ITER>
__global__ void scat_kernel(const uint32_t* __restrict__ bins,
                            const uint32_t* __restrict__ bases,
                            const float* __restrict__ h,     // stride 16
                            float* __restrict__ x,           // stride 10
                            int n, uint32_t cap)
{
    __shared__ float xl[BKT * DIM];      // 40 KB
    const int t = threadIdx.x;
    const int b = blockIdx.x;
    const int n0 = b << BKT_LOG;
    const int nb = min(BKT, n - n0);

    for (int i = t; i < BKT * DIM; i += 256) xl[i] = 0.0f;
    __syncthreads();

    uint32_t lo = bases[b];
    uint32_t hi = min(bases[b + 1], cap);
    const float4* h4 = reinterpret_cast<const float4*>(h);

    for (uint32_t i = lo + t; i < hi; i += 256) {
        uint32_t w = bins[i];
        if (ITER == 1 && !((w >> 29) & 1u)) continue;
        uint32_t s  = w & 0x7FFFFu;
        uint32_t rl = (w >> 19) & (BKT - 1);
        float4 a  = h4[(size_t)s * 4 + 0];
        float4 b4 = h4[(size_t)s * 4 + 1];
        float4 c4 = h4[(size_t)s * 4 + 2];
        float* xr = xl + rl * DIM;
        atomicAdd(xr + 0, a.x);  atomicAdd(xr + 1, a.y);
        atomicAdd(xr + 2, a.z);  atomicAdd(xr + 3, a.w);
        atomicAdd(xr + 4, b4.x); atomicAdd(xr + 5, b4.y);
        atomicAdd(xr + 6, b4.z); atomicAdd(xr + 7, b4.w);
        atomicAdd(xr + 8, c4.x); atomicAdd(xr + 9, c4.y);
    }
    __syncthreads();

    float* xo = x + (size_t)n0 * DIM;
    for (int i = t; i < nb * DIM; i += 256) xo[i] = xl[i];
}

// ---------------------------------------------------------------------------
// init: hbuf[node] = (depth<=2) ? h_in[node] : 0    (stride HS, pads = 0)
// ---------------------------------------------------------------------------
template<int HS>
__global__ void init_mask_kernel(const float* __restrict__ hsrc,  // stride DIM
                                 float* __restrict__ hdst,        // stride HS
                                 const int* __restrict__ depth,
                                 int n)
{
    __shared__ float sh[NTILE * 11];
    const int t = threadIdx.x;
    const int base = blockIdx.x * NTILE;

    const long gbase = (long)base * DIM;
    const long glim  = (long)n * DIM;
    for (int idx = t; idx < NTILE * DIM; idx += NTILE) {
        long g = gbase + idx;
        float v = (g < glim) ? hsrc[g] : 0.0f;
        sh[(idx / DIM) * 11 + (idx % DIM)] = v;
    }
    __syncthreads();

    const int node = base + t;
    if (node < n && depth[node] > 2) {
        #pragma unroll
        for (int c = 0; c < DIM; ++c) sh[t * 11 + c] = 0.0f;
    }
    __syncthreads();

    const long obase = (long)base * HS;
    const long olim  = (long)n * HS;
    for (int idx = t; idx < NTILE * HS; idx += NTILE) {
        long g = obase + idx;
        if (g < olim) {
            int nl = idx / HS, c = idx % HS;
            hdst[g] = (c < DIM) ? sh[nl * 11 + c] : 0.0f;
        }
    }
}

// ---------------------------------------------------------------------------
// GRU update, LDS tile-staged (from round 3, ZEROX removed).
// ---------------------------------------------------------------------------
template<int XS, int HS, int NEXTMASK>
__global__ void gru_kernel(const float* __restrict__ x,
                           const float* __restrict__ h,
                           float* __restrict__ out, int OS,
                           const int* __restrict__ depth, int iter, int n,
                           const float* __restrict__ Wz, const float* __restrict__ bz,
                           const float* __restrict__ Uz, const float* __restrict__ buz,
                           const float* __restrict__ Wr, const float* __restrict__ br,
                           const float* __restrict__ Ur, const float* __restrict__ bur,
                           const float* __restrict__ Wh, const float* __restrict__ bh,
                           const float* __restrict__ Uh, const float* __restrict__ buh)
{
    __shared__ float sx[NTILE * 17];
    __shared__ float shh[NTILE * 17];
    __shared__ float sW[6][100];
    __shared__ float sb[3][10];

    const int t = threadIdx.x;
    if (t < 100) {
        sW[0][t] = Wz[t]; sW[1][t] = Uz[t];
        sW[2][t] = Wr[t]; sW[3][t] = Ur[t];
        sW[4][t] = Wh[t]; sW[5][t] = Uh[t];
    }
    if (t < 10) {
        sb[0][t] = bz[t] + buz[t];
        sb[1][t] = br[t] + bur[t];
        sb[2][t] = bh[t] + buh[t];
    }

    const int base = blockIdx.x * NTILE;

    {   // stage x tile
        const int tile4 = NTILE * XS / 4;
        const long g4base = (long)base * XS / 4;
        const long g4lim  = (long)n * XS / 4;
        const float4* xg = reinterpret_cast<const float4*>(x);
        for (int i4 = t; i4 < tile4; i4 += NTILE) {
            long g = g4base + i4;
            if (g < g4lim) {
                float4 v = xg[g];
                float vv[4] = {v.x, v.y, v.z, v.w};
                int f = i4 * 4;
                int nl = f / XS, c = f % XS;
                #pragma unroll
                for (int k = 0; k < 4; ++k) {
                    if (c < DIM) sx[nl * 17 + c] = vv[k];
                    if (++c == XS) { c = 0; ++nl; }
                }
            }
        }
    }
    {   // stage h tile
        const int tile4 = NTILE * HS / 4;
        const long g4base = (long)base * HS / 4;
        const long g4lim  = (long)n * HS / 4;
        const float4* hg = reinterpret_cast<const float4*>(h);
        for (int i4 = t; i4 < tile4; i4 += NTILE) {
            long g = g4base + i4;
            if (g < g4lim) {
                float4 v = hg[g];
                float vv[4] = {v.x, v.y, v.z, v.w};
                int f = i4 * 4;
                int nl = f / HS, c = f % HS;
                #pragma unroll
                for (int k = 0; k < 4; ++k) {
                    if (c < DIM) shh[nl * 17 + c] = vv[k];
                    if (++c == HS) { c = 0; ++nl; }
                }
            }
        }
    }
    __syncthreads();

    const int node = base + t;
    const bool valid = node < n;
    const int dep = valid ? depth[node] : 99;
    const bool active = valid && (dep + iter <= 2);

    float xv[DIM], hv[DIM], outv[DIM];
    #pragma unroll
    for (int j = 0; j < DIM; ++j) {
        xv[j] = sx[t * 17 + j];
        hv[j] = shh[t * 17 + j];
    }

    if (active) {
        float zz[DIM], rr[DIM];
        #pragma unroll
        for (int i = 0; i < DIM; ++i) {
            float az = sb[0][i];
            float ar = sb[1][i];
            #pragma unroll
            for (int j = 0; j < DIM; ++j) {
                az = fmaf(xv[j], sW[0][i * DIM + j], az);
                az = fmaf(hv[j], sW[1][i * DIM + j], az);
                ar = fmaf(xv[j], sW[2][i * DIM + j], ar);
                ar = fmaf(hv[j], sW[3][i * DIM + j], ar);
            }
            zz[i] = 1.0f / (1.0f + __expf(-az));
            rr[i] = 1.0f / (1.0f + __expf(-ar));
        }
        float rh[DIM];
        #pragma unroll
        for (int j = 0; j < DIM; ++j) rh[j] = rr[j] * hv[j];
        #pragma unroll
        for (int i = 0; i < DIM; ++i) {
            float ah = sb[2][i];
            #pragma unroll
            for (int j = 0; j < DIM; ++j) {
                ah = fmaf(xv[j], sW[4][i * DIM + j], ah);
                ah = fmaf(rh[j], sW[5][i * DIM + j], ah);
            }
            float th = tanhf(ah);
            outv[i] = zz[i] * hv[i] + (1.0f - zz[i]) * th;
        }
    } else {
        #pragma unroll
        for (int i = 0; i < DIM; ++i) outv[i] = hv[i];   // inactive: h already 0
    }

    if (NEXTMASK) {
        const bool keep = valid && (dep + iter + 1 <= 2);
        if (!keep) {
            #pragma unroll
            for (int i = 0; i < DIM; ++i) outv[i] = 0.0f;
        }
    }

    __syncthreads();
    #pragma unroll
    for (int i = 0; i < DIM; ++i) sx[t * 17 + i] = outv[i];
    __syncthreads();

    const long obase = (long)base * OS;
    const long olim  = (long)n * OS;
    for (int idx = t; idx < NTILE * OS; idx += NTILE) {
        long g = obase + idx;
        if (g < olim) {
            int nl = idx / OS, c = idx % OS;
            out[g] = (c < DIM) ? sx[nl * 17 + c] : 0.0f;
        }
    }
}

// ---------------------------------------------------------------------------
// fallback simple atomic scatter (only if ws too small / n too large)
// ---------------------------------------------------------------------------
__global__ void simple_scatter_kernel(const int* __restrict__ recv,
                                      const int* __restrict__ send,
                                      const float* __restrict__ hm,  // stride 10
                                      float* __restrict__ x,         // stride 10
                                      int ne)
{
    const int tid = blockIdx.x * blockDim.x + threadIdx.x;
    const int e = tid / DIM;
    if (e >= ne) return;
    const int c = tid - e * DIM;
    const int s = send[e];
    const float v = hm[(size_t)s * DIM + c];
    if (v != 0.0f) {
        const int r = recv[e];
        unsafeAtomicAdd(x + (size_t)r * DIM + c, v);
    }
}

__global__ void zero_buf_kernel(float4* __restrict__ p, int tot4) {
    int i = blockIdx.x * blockDim.x + threadIdx.x;
    if (i < tot4) p[i] = make_float4(0.0f, 0.0f, 0.0f, 0.0f);
}

extern "C" void kernel_launch(void* const* d_in, const int* in_sizes, int n_in,
                              void* d_out, int out_size, void* d_ws, size_t ws_size,
                              hipStream_t stream) {
    const float* h_in  = (const float*)d_in[0];
    const int*   edges = (const int*)d_in[1];
    const int*   depth = (const int*)d_in[2];
    const float* Wz  = (const float*)d_in[3];
    const float* bz  = (const float*)d_in[4];
    const float* Uz  = (const float*)d_in[5];
    const float* buz = (const float*)d_in[6];
    const float* Wr  = (const float*)d_in[7];
    const float* br  = (const float*)d_in[8];
    const float* Ur  = (const float*)d_in[9];
    const float* bur = (const float*)d_in[10];
    const float* Wh  = (const float*)d_in[11];
    const float* bh  = (const float*)d_in[12];
    const float* Uh  = (const float*)d_in[13];
    const float* buh = (const float*)d_in[14];

    const int n  = in_sizes[0] / DIM;       // 500,000
    const int ne = in_sizes[1] / 2;         // 8,000,000
    const int* recv = edges;
    const int* send = edges + ne;

    const int NB = (n + BKT - 1) >> BKT_LOG;
    const size_t need = ((size_t)n * DIM + (size_t)n * 16) * sizeof(float) + 8192;

    const int BLK = 256;
    const int node_blocks = (n + NTILE - 1) / NTILE;

    if (ws_size >= need && n <= (1 << 19) && NB <= MAXNB) {
        float*    x    = (float*)d_ws;                       // [n*10]
        float*    hbuf = (float*)d_ws + (size_t)n * DIM;     // [n*16]
        uint32_t* meta = (uint32_t*)(hbuf + (size_t)n * 16);
        uint32_t* hist   = meta;          // 512
        uint32_t* bases  = meta + 512;    // 640
        uint32_t* cursor = meta + 1152;   // 512
        uint32_t* bins = (uint32_t*)d_out;
        const uint32_t cap = (uint32_t)out_size;             // n*10 slots

        const int bin_blocks = (ne + EPW - 1) / EPW;

        // ---- bin once (reused by both iterations) ----
        zero_hist_kernel<<<1, MAXNB, 0, stream>>>(hist);
        bin_count_kernel<<<bin_blocks, BLK, 0, stream>>>(recv, send, depth, hist, ne);
        bin_scan_kernel<<<1, MAXNB, 0, stream>>>(hist, bases, cursor, NB);
        bin_emit_kernel<<<bin_blocks, BLK, 0, stream>>>(recv, send, depth, cursor, bins, ne, cap);

        // ---- iteration 0 (active: depth<=2) ----
        init_mask_kernel<16><<<node_blocks, NTILE, 0, stream>>>(h_in, hbuf, depth, n);
        scat_kernel<0><<<NB, BLK, 0, stream>>>(bins, bases, hbuf, x, n, cap);
        gru_kernel<10, 16, 1><<<node_blocks, NTILE, 0, stream>>>(x, hbuf, hbuf, 16, depth, 0, n,
            Wz, bz, Uz, buz, Wr, br, Ur, bur, Wh, bh, Uh, buh);

        // ---- iteration 1 (active: depth<=1) ----
        scat_kernel<1><<<NB, BLK, 0, stream>>>(bins, bases, hbuf, x, n, cap);
        gru_kernel<10, 16, 0><<<node_blocks, NTILE, 0, stream>>>(x, hbuf, (float*)d_out, DIM, depth, 1, n,
            Wz, bz, Uz, buz, Wr, br, Ur, bur, Wh, bh, Uh, buh);
    } else {
        // fallback: unpadded atomic path, h in d_out
        float* x    = (float*)d_ws;
        float* hbuf = (float*)d_out;
        const int nwork = ne * DIM;
        const int edge_blocks = (nwork + BLK - 1) / BLK;
        const int x_tot4 = (n * DIM) / 4;
        const int xz_blocks = (x_tot4 + BLK - 1) / BLK;

        init_mask_kernel<10><<<node_blocks, NTILE, 0, stream>>>(h_in, hbuf, depth, n);
        zero_buf_kernel<<<xz_blocks, BLK, 0, stream>>>((float4*)x, x_tot4);
        simple_scatter_kernel<<<edge_blocks, BLK, 0, stream>>>(recv, send, hbuf, x, ne);
        gru_kernel<10, 10, 1><<<node_blocks, NTILE, 0, stream>>>(x, hbuf, hbuf, DIM, depth, 0, n,
            Wz, bz, Uz, buz, Wr, br, Ur, bur, Wh, bh, Uh, buh);
        zero_buf_kernel<<<xz_blocks, BLK, 0, stream>>>((float4*)x, x_tot4);
        simple_scatter_kernel<<<edge_blocks, BLK, 0, stream>>>(recv, send, hbuf, x, ne);
        gru_kernel<10, 10, 0><<<node_blocks, NTILE, 0, stream>>>(x, hbuf, hbuf, DIM, depth, 1, n,
            Wz, bz, Uz, buz, Wr, br, Ur, bur, Wh, bh, Uh, buh);
    }
}

// Round 6
// 859.159 us; speedup vs baseline: 1.2183x; 1.0743x over previous
//
#include <hip/hip_runtime.h>
#include <math.h>
#include <stdint.h>

#define DIM 10
#define NTILE 256
#define BKT_LOG 8
#define BKT 256                   // nodes per bucket
#define NBMAX 2048
#define EPW 4096                  // edges per WG in binning
#define KPT (EPW / 256)           // 16 edges per thread
#define CAPB 2556                 // bin slots per bucket (NB*CAPB <= out_size)
#define CAPF 1152                 // front region (edges useful at iter 1)
#define CAPK (CAPB - CAPF)        // back region (iter-0-only edges)
#define OVFCAP 32768

// ---------------------------------------------------------------------------
// meta (u32) in ws after x,hbuf: cntF[2048] | cntB[2048] | ovfc[8] | ovf[OVFCAP]
// ---------------------------------------------------------------------------

__global__ void meta_zero_kernel(uint32_t* __restrict__ meta, int tot) {
    int i = blockIdx.x * blockDim.x + threadIdx.x;
    if (i < tot) meta[i] = 0;
}

// ---------------------------------------------------------------------------
// single-pass binning. Bucket b owns bins[b*CAPB .. b*CAPB+CAPB):
//   front [0,CAPF): edges with dr<=1 && ds<=1 (useful both iters)
//   back  (grows from end): edges useful only at iter 0 (dr,ds<=2)
// word = s(19b) | rl(8b)<<19 | flag<<27.  Spill -> ovf list (edge ids).
// ---------------------------------------------------------------------------
__global__ void bin_kernel(const int* __restrict__ recv,
                           const int* __restrict__ send,
                           const int* __restrict__ depth,
                           uint32_t* __restrict__ cntF,
                           uint32_t* __restrict__ cntB,
                           uint32_t* __restrict__ ovfc,
                           uint32_t* __restrict__ ovf,
                           uint32_t* __restrict__ bins,
                           int ne)
{
    __shared__ uint32_t lh[NBMAX];     // packed counts: front lo16, back hi16
    __shared__ uint32_t wgF[NBMAX];
    __shared__ uint32_t wgB[NBMAX];
    const int t = threadIdx.x;
    for (int i = t; i < NBMAX; i += 256) lh[i] = 0;
    __syncthreads();

    const int base = blockIdx.x * EPW;
    int rA[KPT], sA[KPT];
    uint32_t fl = 0;                   // 2 bits per edge: bit0 keep0, bit1 flag1

    #pragma unroll
    for (int k = 0; k < KPT; ++k) {
        int e = base + k * 256 + t;
        int r = 0, s = 0;
        if (e < ne) {
            r = recv[e]; s = send[e];
            int dr = depth[r], ds = depth[s];
            if (dr <= 2 && ds <= 2) {
                bool f1 = (dr <= 1) && (ds <= 1);
                fl |= (f1 ? 3u : 1u) << (2 * k);
                atomicAdd(&lh[r >> BKT_LOG], f1 ? 1u : 0x10000u);
            }
        }
        rA[k] = r; sA[k] = s;
    }
    __syncthreads();

    for (int i = t; i < NBMAX; i += 256) {
        uint32_t v = lh[i];
        if (v) {
            uint32_t f = v & 0xffffu, kb = v >> 16;
            if (f)  wgF[i] = atomicAdd(&cntF[i], f);
            if (kb) wgB[i] = atomicAdd(&cntB[i], kb);
        }
    }
    __syncthreads();
    for (int i = t; i < NBMAX; i += 256) lh[i] = 0;   // reuse as local cursors
    __syncthreads();

    #pragma unroll
    for (int k = 0; k < KPT; ++k) {
        if ((fl >> (2 * k)) & 1u) {
            int r = rA[k], s = sA[k];
            int b = r >> BKT_LOG;
            bool f1 = (fl >> (2 * k)) & 2u;
            uint32_t w = (uint32_t)s | ((uint32_t)(r & (BKT - 1)) << 19)
                       | (f1 ? (1u << 27) : 0u);
            if (f1) {
                uint32_t o = atomicAdd(&lh[b], 1u) & 0xffffu;
                uint32_t pos = wgF[b] + o;
                if (pos < CAPF) bins[(size_t)b * CAPB + pos] = w;
                else { uint32_t oi = atomicAdd(ovfc, 1u);
                       if (oi < OVFCAP) ovf[oi] = (uint32_t)(base + k * 256 + t); }
            } else {
                uint32_t o = atomicAdd(&lh[b], 0x10000u) >> 16;
                uint32_t pos = wgB[b] + o;
                if (pos < CAPK) bins[(size_t)b * CAPB + (CAPB - 1) - pos] = w;
                else { uint32_t oi = atomicAdd(ovfc, 1u);
                       if (oi < OVFCAP) ovf[oi] = (uint32_t)(base + k * 256 + t); }
            }
        }
    }
}

// ---------------------------------------------------------------------------
// scatter: one WG per 256-node bucket; LDS accumulation; plain-store flush.
// ITER==0 reads front+back segments, ITER==1 front only.
// ---------------------------------------------------------------------------
template<int ITER>
__global__ void scat_kernel(const uint32_t* __restrict__ bins,
                            const uint32_t* __restrict__ cntF,
                            const uint32_t* __restrict__ cntB,
                            const float* __restrict__ h,     // stride 16
                            float* __restrict__ x,           // stride 10
                            int n)
{
    __shared__ float xl[BKT * DIM];      // 10 KB
    const int t = threadIdx.x;
    const int b = blockIdx.x;
    const int n0 = b << BKT_LOG;
    const int nb = min(BKT, n - n0);

    for (int i = t; i < BKT * DIM; i += 256) xl[i] = 0.0f;
    __syncthreads();

    const size_t base = (size_t)b * CAPB;
    const int fc = (int)min(cntF[b], (uint32_t)CAPF);
    int tot = fc, boff = 0;
    if (ITER == 0) {
        int bc = (int)min(cntB[b], (uint32_t)CAPK);
        tot = fc + bc;
        boff = CAPB - bc - fc;           // maps i in [fc,tot) -> end segment
    }
    const float4* h4 = reinterpret_cast<const float4*>(h);

    for (int i = t; i < tot; i += 256) {
        size_t idx = base + (size_t)((ITER == 0 && i >= fc) ? (i + boff) : i);
        uint32_t w = bins[idx];
        uint32_t s  = w & 0x7FFFFu;
        uint32_t rl = (w >> 19) & (BKT - 1);
        float4 a  = h4[(size_t)s * 4 + 0];
        float4 b4 = h4[(size_t)s * 4 + 1];
        float4 c4 = h4[(size_t)s * 4 + 2];
        float* xr = xl + rl * DIM;
        atomicAdd(xr + 0, a.x);  atomicAdd(xr + 1, a.y);
        atomicAdd(xr + 2, a.z);  atomicAdd(xr + 3, a.w);
        atomicAdd(xr + 4, b4.x); atomicAdd(xr + 5, b4.y);
        atomicAdd(xr + 6, b4.z); atomicAdd(xr + 7, b4.w);
        atomicAdd(xr + 8, c4.x); atomicAdd(xr + 9, c4.y);
    }
    __syncthreads();

    float* xo = x + (size_t)n0 * DIM;
    for (int i = t; i < nb * DIM; i += 256) xo[i] = xl[i];
}

// ---------------------------------------------------------------------------
// apply spilled edges with global HW atomics (runs after scat's flush)
// ---------------------------------------------------------------------------
__global__ void ovf_apply_kernel(const uint32_t* __restrict__ ovfc,
                                 const uint32_t* __restrict__ ovf,
                                 const int* __restrict__ recv,
                                 const int* __restrict__ send,
                                 const int* __restrict__ depth,
                                 const float* __restrict__ h,   // stride 16
                                 float* __restrict__ x,         // stride 10
                                 int iter)
{
    const uint32_t cnt = min(*ovfc, (uint32_t)OVFCAP);
    const float4* h4 = reinterpret_cast<const float4*>(h);
    for (uint32_t i = blockIdx.x * blockDim.x + threadIdx.x; i < cnt;
         i += gridDim.x * blockDim.x) {
        int e = (int)ovf[i];
        int r = recv[e], s = send[e];
        if (iter == 1 && (depth[r] > 1 || depth[s] > 1)) continue;
        float4 a  = h4[(size_t)s * 4 + 0];
        float4 b4 = h4[(size_t)s * 4 + 1];
        float4 c4 = h4[(size_t)s * 4 + 2];
        float* xr = x + (size_t)r * DIM;
        unsafeAtomicAdd(xr + 0, a.x);  unsafeAtomicAdd(xr + 1, a.y);
        unsafeAtomicAdd(xr + 2, a.z);  unsafeAtomicAdd(xr + 3, a.w);
        unsafeAtomicAdd(xr + 4, b4.x); unsafeAtomicAdd(xr + 5, b4.y);
        unsafeAtomicAdd(xr + 6, b4.z); unsafeAtomicAdd(xr + 7, b4.w);
        unsafeAtomicAdd(xr + 8, c4.x); unsafeAtomicAdd(xr + 9, c4.y);
    }
}

// ---------------------------------------------------------------------------
// init: hbuf[node] = (depth<=2) ? h_in[node] : 0    (stride HS, pads = 0)
// ---------------------------------------------------------------------------
template<int HS>
__global__ void init_mask_kernel(const float* __restrict__ hsrc,  // stride DIM
                                 float* __restrict__ hdst,        // stride HS
                                 const int* __restrict__ depth,
                                 int n)
{
    __shared__ float sh[NTILE * 11];
    const int t = threadIdx.x;
    const int base = blockIdx.x * NTILE;

    const long gbase = (long)base * DIM;
    const long glim  = (long)n * DIM;
    for (int idx = t; idx < NTILE * DIM; idx += NTILE) {
        long g = gbase + idx;
        float v = (g < glim) ? hsrc[g] : 0.0f;
        sh[(idx / DIM) * 11 + (idx % DIM)] = v;
    }
    __syncthreads();

    const int node = base + t;
    if (node < n && depth[node] > 2) {
        #pragma unroll
        for (int c = 0; c < DIM; ++c) sh[t * 11 + c] = 0.0f;
    }
    __syncthreads();

    const long obase = (long)base * HS;
    const long olim  = (long)n * HS;
    for (int idx = t; idx < NTILE * HS; idx += NTILE) {
        long g = obase + idx;
        if (g < olim) {
            int nl = idx / HS, c = idx % HS;
            hdst[g] = (c < DIM) ? sh[nl * 11 + c] : 0.0f;
        }
    }
}

// ---------------------------------------------------------------------------
// GRU update, LDS tile-staged.
// ---------------------------------------------------------------------------
template<int XS, int HS, int NEXTMASK>
__global__ void gru_kernel(const float* __restrict__ x,
                           const float* __restrict__ h,
                           float* __restrict__ out, int OS,
                           const int* __restrict__ depth, int iter, int n,
                           const float* __restrict__ Wz, const float* __restrict__ bz,
                           const float* __restrict__ Uz, const float* __restrict__ buz,
                           const float* __restrict__ Wr, const float* __restrict__ br,
                           const float* __restrict__ Ur, const float* __restrict__ bur,
                           const float* __restrict__ Wh, const float* __restrict__ bh,
                           const float* __restrict__ Uh, const float* __restrict__ buh)
{
    __shared__ float sx[NTILE * 17];
    __shared__ float shh[NTILE * 17];
    __shared__ float sW[6][100];
    __shared__ float sb[3][10];

    const int t = threadIdx.x;
    if (t < 100) {
        sW[0][t] = Wz[t]; sW[1][t] = Uz[t];
        sW[2][t] = Wr[t]; sW[3][t] = Ur[t];
        sW[4][t] = Wh[t]; sW[5][t] = Uh[t];
    }
    if (t < 10) {
        sb[0][t] = bz[t] + buz[t];
        sb[1][t] = br[t] + bur[t];
        sb[2][t] = bh[t] + buh[t];
    }

    const int base = blockIdx.x * NTILE;

    {   // stage x tile
        const int tile4 = NTILE * XS / 4;
        const long g4base = (long)base * XS / 4;
        const long g4lim  = (long)n * XS / 4;
        const float4* xg = reinterpret_cast<const float4*>(x);
        for (int i4 = t; i4 < tile4; i4 += NTILE) {
            long g = g4base + i4;
            if (g < g4lim) {
                float4 v = xg[g];
                float vv[4] = {v.x, v.y, v.z, v.w};
                int f = i4 * 4;
                int nl = f / XS, c = f % XS;
                #pragma unroll
                for (int k = 0; k < 4; ++k) {
                    if (c < DIM) sx[nl * 17 + c] = vv[k];
                    if (++c == XS) { c = 0; ++nl; }
                }
            }
        }
    }
    {   // stage h tile
        const int tile4 = NTILE * HS / 4;
        const long g4base = (long)base * HS / 4;
        const long g4lim  = (long)n * HS / 4;
        const float4* hg = reinterpret_cast<const float4*>(h);
        for (int i4 = t; i4 < tile4; i4 += NTILE) {
            long g = g4base + i4;
            if (g < g4lim) {
                float4 v = hg[g];
                float vv[4] = {v.x, v.y, v.z, v.w};
                int f = i4 * 4;
                int nl = f / HS, c = f % HS;
                #pragma unroll
                for (int k = 0; k < 4; ++k) {
                    if (c < DIM) shh[nl * 17 + c] = vv[k];
                    if (++c == HS) { c = 0; ++nl; }
                }
            }
        }
    }
    __syncthreads();

    const int node = base + t;
    const bool valid = node < n;
    const int dep = valid ? depth[node] : 99;
    const bool active = valid && (dep + iter <= 2);

    float xv[DIM], hv[DIM], outv[DIM];
    #pragma unroll
    for (int j = 0; j < DIM; ++j) {
        xv[j] = sx[t * 17 + j];
        hv[j] = shh[t * 17 + j];
    }

    if (active) {
        float zz[DIM], rr[DIM];
        #pragma unroll
        for (int i = 0; i < DIM; ++i) {
            float az = sb[0][i];
            float ar = sb[1][i];
            #pragma unroll
            for (int j = 0; j < DIM; ++j) {
                az = fmaf(xv[j], sW[0][i * DIM + j], az);
                az = fmaf(hv[j], sW[1][i * DIM + j], az);
                ar = fmaf(xv[j], sW[2][i * DIM + j], ar);
                ar = fmaf(hv[j], sW[3][i * DIM + j], ar);
            }
            zz[i] = 1.0f / (1.0f + __expf(-az));
            rr[i] = 1.0f / (1.0f + __expf(-ar));
        }
        float rh[DIM];
        #pragma unroll
        for (int j = 0; j < DIM; ++j) rh[j] = rr[j] * hv[j];
        #pragma unroll
        for (int i = 0; i < DIM; ++i) {
            float ah = sb[2][i];
            #pragma unroll
            for (int j = 0; j < DIM; ++j) {
                ah = fmaf(xv[j], sW[4][i * DIM + j], ah);
                ah = fmaf(rh[j], sW[5][i * DIM + j], ah);
            }
            float th = tanhf(ah);
            outv[i] = zz[i] * hv[i] + (1.0f - zz[i]) * th;
        }
    } else {
        #pragma unroll
        for (int i = 0; i < DIM; ++i) outv[i] = hv[i];   // inactive: h already 0
    }

    if (NEXTMASK) {
        const bool keep = valid && (dep + iter + 1 <= 2);
        if (!keep) {
            #pragma unroll
            for (int i = 0; i < DIM; ++i) outv[i] = 0.0f;
        }
    }

    __syncthreads();
    #pragma unroll
    for (int i = 0; i < DIM; ++i) sx[t * 17 + i] = outv[i];
    __syncthreads();

    const long obase = (long)base * OS;
    const long olim  = (long)n * OS;
    for (int idx = t; idx < NTILE * OS; idx += NTILE) {
        long g = obase + idx;
        if (g < olim) {
            int nl = idx / OS, c = idx % OS;
            out[g] = (c < DIM) ? sx[nl * 17 + c] : 0.0f;
        }
    }
}

// ---------------------------------------------------------------------------
// fallback simple atomic scatter (only if ws too small / n too large)
// ---------------------------------------------------------------------------
__global__ void simple_scatter_kernel(const int* __restrict__ recv,
                                      const int* __restrict__ send,
                                      const float* __restrict__ hm,  // stride 10
                                      float* __restrict__ x,         // stride 10
                                      int ne)
{
    const int tid = blockIdx.x * blockDim.x + threadIdx.x;
    const int e = tid / DIM;
    if (e >= ne) return;
    const int c = tid - e * DIM;
    const int s = send[e];
    const float v = hm[(size_t)s * DIM + c];
    if (v != 0.0f) {
        const int r = recv[e];
        unsafeAtomicAdd(x + (size_t)r * DIM + c, v);
    }
}

__global__ void zero_buf_kernel(float4* __restrict__ p, int tot4) {
    int i = blockIdx.x * blockDim.x + threadIdx.x;
    if (i < tot4) p[i] = make_float4(0.0f, 0.0f, 0.0f, 0.0f);
}

extern "C" void kernel_launch(void* const* d_in, const int* in_sizes, int n_in,
                              void* d_out, int out_size, void* d_ws, size_t ws_size,
                              hipStream_t stream) {
    const float* h_in  = (const float*)d_in[0];
    const int*   edges = (const int*)d_in[1];
    const int*   depth = (const int*)d_in[2];
    const float* Wz  = (const float*)d_in[3];
    const float* bz  = (const float*)d_in[4];
    const float* Uz  = (const float*)d_in[5];
    const float* buz = (const float*)d_in[6];
    const float* Wr  = (const float*)d_in[7];
    const float* br  = (const float*)d_in[8];
    const float* Ur  = (const float*)d_in[9];
    const float* bur = (const float*)d_in[10];
    const float* Wh  = (const float*)d_in[11];
    const float* bh  = (const float*)d_in[12];
    const float* Uh  = (const float*)d_in[13];
    const float* buh = (const float*)d_in[14];

    const int n  = in_sizes[0] / DIM;       // 500,000
    const int ne = in_sizes[1] / 2;         // 8,000,000
    const int* recv = edges;
    const int* send = edges + ne;

    const int NB = (n + BKT - 1) >> BKT_LOG;
    const size_t meta_words = 2 * NBMAX + 8 + OVFCAP;
    const size_t need = ((size_t)n * DIM + (size_t)n * 16) * sizeof(float)
                      + meta_words * sizeof(uint32_t);

    const int BLK = 256;
    const int node_blocks = (n + NTILE - 1) / NTILE;

    if (ws_size >= need && n <= (1 << 19) && NB <= NBMAX &&
        (size_t)NB * CAPB <= (size_t)out_size) {
        float*    x    = (float*)d_ws;                       // [n*10]
        float*    hbuf = (float*)d_ws + (size_t)n * DIM;     // [n*16]
        uint32_t* meta = (uint32_t*)(hbuf + (size_t)n * 16);
        uint32_t* cntF = meta;                // NBMAX
        uint32_t* cntB = meta + NBMAX;        // NBMAX
        uint32_t* ovfc = meta + 2 * NBMAX;    // 8 (1 used)
        uint32_t* ovf  = meta + 2 * NBMAX + 8;
        uint32_t* bins = (uint32_t*)d_out;

        const int meta_tot = 2 * NBMAX + 1;
        const int bin_blocks = (ne + EPW - 1) / EPW;

        meta_zero_kernel<<<(meta_tot + BLK - 1) / BLK, BLK, 0, stream>>>(meta, meta_tot);
        bin_kernel<<<bin_blocks, BLK, 0, stream>>>(recv, send, depth,
                                                   cntF, cntB, ovfc, ovf, bins, ne);
        init_mask_kernel<16><<<node_blocks, NTILE, 0, stream>>>(h_in, hbuf, depth, n);

        // ---- iteration 0 (active: depth<=2) ----
        scat_kernel<0><<<NB, BLK, 0, stream>>>(bins, cntF, cntB, hbuf, x, n);
        ovf_apply_kernel<<<16, BLK, 0, stream>>>(ovfc, ovf, recv, send, depth, hbuf, x, 0);
        gru_kernel<10, 16, 1><<<node_blocks, NTILE, 0, stream>>>(x, hbuf, hbuf, 16, depth, 0, n,
            Wz, bz, Uz, buz, Wr, br, Ur, bur, Wh, bh, Uh, buh);

        // ---- iteration 1 (active: depth<=1) ----
        scat_kernel<1><<<NB, BLK, 0, stream>>>(bins, cntF, cntB, hbuf, x, n);
        ovf_apply_kernel<<<16, BLK, 0, stream>>>(ovfc, ovf, recv, send, depth, hbuf, x, 1);
        gru_kernel<10, 16, 0><<<node_blocks, NTILE, 0, stream>>>(x, hbuf, (float*)d_out, DIM, depth, 1, n,
            Wz, bz, Uz, buz, Wr, br, Ur, bur, Wh, bh, Uh, buh);
    } else {
        // fallback: unpadded atomic path, h in d_out
        float* x    = (float*)d_ws;
        float* hbuf = (float*)d_out;
        const int nwork = ne * DIM;
        const int edge_blocks = (nwork + BLK - 1) / BLK;
        const int x_tot4 = (n * DIM) / 4;
        const int xz_blocks = (x_tot4 + BLK - 1) / BLK;

        init_mask_kernel<10><<<node_blocks, NTILE, 0, stream>>>(h_in, hbuf, depth, n);
        zero_buf_kernel<<<xz_blocks, BLK, 0, stream>>>((float4*)x, x_tot4);
        simple_scatter_kernel<<<edge_blocks, BLK, 0, stream>>>(recv, send, hbuf, x, ne);
        gru_kernel<10, 10, 1><<<node_blocks, NTILE, 0, stream>>>(x, hbuf, hbuf, DIM, depth, 0, n,
            Wz, bz, Uz, buz, Wr, br, Ur, bur, Wh, bh, Uh, buh);
        zero_buf_kernel<<<xz_blocks, BLK, 0, stream>>>((float4*)x, x_tot4);
        simple_scatter_kernel<<<edge_blocks, BLK, 0, stream>>>(recv, send, hbuf, x, ne);
        gru_kernel<10, 10, 0><<<node_blocks, NTILE, 0, stream>>>(x, hbuf, hbuf, DIM, depth, 1, n,
            Wz, bz, Uz, buz, Wr, br, Ur, bur, Wh, bh, Uh, buh);
    }
}